// Round 6
// baseline (296.331 us; speedup 1.0000x reference)
//
#include <hip/hip_runtime.h>

#define NPTS 65536
#define KC   1024
#define DD   512

using bf16x8 = __attribute__((ext_vector_type(8))) __bf16;
using f32x4  = __attribute__((ext_vector_type(4))) float;

// ---- async global->LDS, 16B per lane. LDS dest = wave-uniform base + lane*16.
__device__ __forceinline__ void gld_lds16(const void* g, void* lds_base) {
  __builtin_amdgcn_global_load_lds(
      (const __attribute__((address_space(1))) unsigned int*)(uintptr_t)g,
      (__attribute__((address_space(3))) unsigned int*)(unsigned int)(uintptr_t)lds_base,
      16, 0, 0);
}

// pack float4 -> 4 bf16 (truncation)
__device__ __forceinline__ uint2 pack4(const float4& v) {
  uint2 r;
  r.x = (__float_as_uint(v.x) >> 16) | (__float_as_uint(v.y) & 0xffff0000u);
  r.y = (__float_as_uint(v.z) >> 16) | (__float_as_uint(v.w) & 0xffff0000u);
  return r;
}

// ================= FAST PATH =================

// merged prep (R4 structure): blocks [0,4096) = x section, 4 rows/wave;
// blocks [4096,4352) = centers section.
// R6 change: centers are written K-MAJOR-CHUNKED (cbT): 16B chunk l of row c
// lands at uint4 index (l>>2)*4096 + c*4 + (l&3), i.e. [kt][col][q].  This
// makes gemm's direct-from-L2 B-fragment loads fully coalesced (1KB/wave).
// R2 LESSON kept: no single-address atomics.
__global__ __launch_bounds__(256) void prep_kernel(
    const float* __restrict__ x, const int* __restrict__ y,
    const float* __restrict__ centers, uint4* __restrict__ xb,
    uint4* __restrict__ cbT, float* __restrict__ c2,
    float* __restrict__ partial) {
  const int w = threadIdx.x >> 6, l = threadIdx.x & 63;
  if (blockIdx.x >= 4096) {   // centers section
    const int row = (blockIdx.x - 4096) * 4 + w;
    const float4* cf4 = (const float4*)centers;
    float4 a = cf4[row * 128 + 2 * l];
    float4 b = cf4[row * 128 + 2 * l + 1];
    uint2 pa = pack4(a), pb = pack4(b);
    cbT[(l >> 2) * 4096 + row * 4 + (l & 3)] = make_uint4(pa.x, pa.y, pb.x, pb.y);
    float s = a.x * a.x + a.y * a.y + a.z * a.z + a.w * a.w +
              b.x * b.x + b.y * b.y + b.z * b.z + b.w * b.w;
#pragma unroll
    for (int off = 32; off; off >>= 1) s += __shfl_down(s, off, 64);
    if (l == 0) c2[row] = s;
    return;
  }
  const int rbase = blockIdx.x * 16 + w * 4;
  const float4* xr = (const float4*)(x + (size_t)rbase * DD);
  float4 a[4], b[4];
#pragma unroll
  for (int r = 0; r < 4; r++) {
    a[r] = xr[r * 128 + 2 * l];
    b[r] = xr[r * 128 + 2 * l + 1];
  }
  int yr[4];
#pragma unroll
  for (int r = 0; r < 4; r++) yr[r] = y[rbase + r];
  float4 ca[4], cb4[4];
#pragma unroll
  for (int r = 0; r < 4; r++) {
    const float4* cr = (const float4*)(centers + (size_t)yr[r] * DD);
    ca[r]  = cr[2 * l];
    cb4[r] = cr[2 * l + 1];
  }
#pragma unroll
  for (int r = 0; r < 4; r++) {
    uint2 pa = pack4(a[r]), pb = pack4(b[r]);
    xb[(size_t)(rbase + r) * 64 + l] = make_uint4(pa.x, pa.y, pb.x, pb.y);
  }
  float s = 0.f;
#pragma unroll
  for (int r = 0; r < 4; r++) {
    float d0 = a[r].x - ca[r].x, d1 = a[r].y - ca[r].y;
    float d2 = a[r].z - ca[r].z, d3 = a[r].w - ca[r].w;
    float d4 = b[r].x - cb4[r].x, d5 = b[r].y - cb4[r].y;
    float d6 = b[r].z - cb4[r].z, d7 = b[r].w - cb4[r].w;
    s += d0 * d0 + d1 * d1 + d2 * d2 + d3 * d3 +
         d4 * d4 + d5 * d5 + d6 * d6 + d7 * d7;
  }
#pragma unroll
  for (int off = 32; off; off >>= 1) s += __shfl_down(s, off, 64);
  __shared__ float ps[4];
  if (l == 0) ps[w] = s;
  __syncthreads();
  if (threadIdx.x == 0) partial[blockIdx.x] = ps[0] + ps[1] + ps[2] + ps[3];
}

// bf16 MFMA argmin — R6: A-resident LDS + B-from-L2-registers.
//
// R5 post-mortem: three schedules all ~78us / 36% MfmaUtil with identical
// LDS traffic (128KB/tile/CU ~ LDS pipe saturation) + full barrier lockstep.
// Fix is structural, not scheduling:
//  - BM=128, 512 blocks x 512 threads (8 waves, wave tile 64x64, acc 64).
//  - A panel (128x512 bf16 = 128KB) staged ONCE into LDS during pass 0
//    (lead-4 counted vmcnt(1), 1 gld_lds/wave/tile); passes 1-3 have NO
//    barriers, NO staging, NO manual waitcnt — waves drift and overlap.
//  - B (1MB, L2-resident, shared by all blocks) is never staged: fragments
//    are loaded straight to registers from the K-major cbT layout (1KB
//    coalesced wave reads); the COMPILER emits counted vmcnt for them.
//    B double-buffered bA/bB via 2-tile unroll (static names, rule 20).
//  - LDS/tile/CU drops 128KB -> 40KB; A global traffic 256MB -> 64MB.
//  - No setprio (m190: hurts lockstep GEMM; R0 without it was best).
// LDS swizzle on A (verified 0-conflict): chunk-XOR involution, both sides.
// LDS: As 128KB + c2s 4KB = 132KB -> 1 block/CU.  Regs ~110 + 64 acc.
__global__ __launch_bounds__(512, 2) void gemm_argmin(
    const uint4* __restrict__ xb, const uint4* __restrict__ cbT,
    const float* __restrict__ c2, const float* __restrict__ partial,
    float* __restrict__ loss_out, float* __restrict__ ynew_out) {
  __shared__ uint4 As[8192];   // 16 K-tiles x (128 rows x 4 chunks)
  __shared__ float c2s[KC];
  __shared__ float ls[8];

  const int t = threadIdx.x;
  const int w = t >> 6, l = t & 63;
  const int wm = w >> 2, wn = w & 3;     // wave tile: 64 rows x 64 cols
  const int q4 = l >> 4, m16 = l & 15;
  const int row0 = blockIdx.x * 128;

  c2s[t] = c2[t];
  c2s[t + 512] = c2[t + 512];

  // A staging: wave w owns rows [16w,16w+16); lane l -> row l>>2, source
  // chunk pre-swizzled so linear gld_lds dest = swizzled layout (rule 21).
  const int srow = l >> 2;
  const int schk = (l & 3) ^ ((l >> 3) & 3);
  const uint4* aB = xb + ((size_t)(row0 + w * 16 + srow) * 64 + schk);
  // A fragment read: row r = wm*64 + i*16 + m16, slot = kt*512 + r*4 + xs
  const int xs = q4 ^ ((m16 >> 1) & 3);
  const int al0 = (wm * 64 + m16) * 4 + xs;
  // B fragment lane offset (uint4 units): col = wn*64 + j*16 + m16, + q4
  const int bl0 = (wn * 64 + m16) * 4 + q4;

  // prologue: stage A K-tiles 0..3; load B(0) -> bA
#pragma unroll
  for (int p = 0; p < 4; p++)
    gld_lds16(aB + p * 4, &As[p * 512 + w * 64]);

  bf16x8 bA[4], bB[4];
#pragma unroll
  for (int j = 0; j < 4; j++)
    bA[j] = *(const bf16x8*)(cbT + bl0 + j * 64);

  f32x4 acc[4][4];
#pragma unroll
  for (int i = 0; i < 4; i++)
#pragma unroll
    for (int j = 0; j < 4; j++) acc[i][j] = (f32x4){0.f, 0.f, 0.f, 0.f};

  float best[16];
  int bi_[16];
#pragma unroll
  for (int i = 0; i < 16; i++) { best[i] = 3.4e38f; bi_[i] = 0; }

  // force A(0) resident (A1..3 + B0 still in flight; compiler guards B0)
  asm volatile("s_waitcnt vmcnt(7)" ::: "memory");
  __builtin_amdgcn_s_barrier();

#define FOLD(P)                                                             \
  {                                                                         \
    const int n0f = (P) * 256;                                              \
    _Pragma("unroll")                                                       \
    for (int j = 0; j < 4; j++) {                                           \
      const int n = n0f + wn * 64 + j * 16 + m16;                           \
      const float cc = c2s[n];                                              \
      _Pragma("unroll")                                                     \
      for (int i = 0; i < 4; i++)                                           \
        _Pragma("unroll")                                                   \
        for (int r = 0; r < 4; r++) {                                       \
          float v = fmaf(-2.f, acc[i][j][r], cc);                           \
          const int bidx = i * 4 + r;                                       \
          if (v < best[bidx]) { best[bidx] = v; bi_[bidx] = n; }            \
          acc[i][j][r] = 0.f;                                               \
        }                                                                   \
    }                                                                       \
  }

  // ---- pass 0: tiles 0..15, with staging + barriers (counted vmcnt) ----
#define TILE_P0(T, BC, BN)                                                  \
  {                                                                         \
    const int kt = (T) & 15;                                                \
    if ((T) < 15) {                                                         \
      const uint4* bp = cbT + ((T) + 1) * 4096;                             \
      _Pragma("unroll")                                                     \
      for (int j = 0; j < 4; j++)                                           \
        BN[j] = *(const bf16x8*)(bp + bl0 + j * 64);                        \
    }                                                                       \
    if ((T) < 12)                                                           \
      gld_lds16(aB + ((T) + 4) * 4, &As[((T) + 4) * 512 + w * 64]);         \
    bf16x8 af[4];                                                           \
    _Pragma("unroll")                                                       \
    for (int i = 0; i < 4; i++)                                             \
      af[i] = *(const bf16x8*)&As[kt * 512 + al0 + i * 64];                 \
    _Pragma("unroll")                                                       \
    for (int j = 0; j < 4; j++)                                             \
      _Pragma("unroll")                                                     \
      for (int i = 0; i < 4; i++)                                           \
        acc[i][j] = __builtin_amdgcn_mfma_f32_16x16x32_bf16(af[i], BC[j], acc[i][j], 0, 0, 0); \
    if ((T) == 15) FOLD(0);                                                 \
    if ((T) < 12) asm volatile("s_waitcnt vmcnt(1)" ::: "memory");          \
    else          asm volatile("s_waitcnt vmcnt(0)" ::: "memory");          \
    __builtin_amdgcn_s_barrier();                                           \
  }

#pragma unroll 1
  for (int s = 0; s < 8; ++s) {
    const int te = 2 * s;
    TILE_P0(te, bA, bB);
    TILE_P0(te + 1, bB, bA);
  }
#undef TILE_P0

  // ---- passes 1-3: tiles 16..63 — NO barriers, NO staging, NO asm ----
  // A is fully LDS-resident; B(t+1) loads are plain C -> compiler emits
  // counted vmcnt; waves drift freely (cross-wave MFMA/LDS/VMEM overlap).
#define TILE_MAIN(T, BC, BN)                                                \
  {                                                                         \
    const int kt = (T) & 15;                                                \
    if ((T) < 63) {                                                         \
      const int tn = (T) + 1;                                               \
      const uint4* bp = cbT + (tn & 15) * 4096 + ((tn >> 4) * 256) * 4;     \
      _Pragma("unroll")                                                     \
      for (int j = 0; j < 4; j++)                                           \
        BN[j] = *(const bf16x8*)(bp + bl0 + j * 64);                        \
    }                                                                       \
    bf16x8 af[4];                                                           \
    _Pragma("unroll")                                                       \
    for (int i = 0; i < 4; i++)                                             \
      af[i] = *(const bf16x8*)&As[kt * 512 + al0 + i * 64];                 \
    _Pragma("unroll")                                                       \
    for (int j = 0; j < 4; j++)                                             \
      _Pragma("unroll")                                                     \
      for (int i = 0; i < 4; i++)                                           \
        acc[i][j] = __builtin_amdgcn_mfma_f32_16x16x32_bf16(af[i], BC[j], acc[i][j], 0, 0, 0); \
    if (((T) & 15) == 15) FOLD((T) >> 4);                                   \
  }

#pragma unroll 1
  for (int s = 8; s < 32; ++s) {
    const int te = 2 * s;
    TILE_MAIN(te, bA, bB);
    TILE_MAIN(te + 1, bB, bA);
  }
#undef TILE_MAIN
#undef FOLD

  __syncthreads();   // all waves done before As is reused for the merge

  // per-wave reduce across the 16 m16-lanes (offsets <16 stay in q4 group)
  float* mv = (float*)As;                 // [4][128] values
  int*   mi = (int*)((char*)As + 2048);   // [4][128] indices
#pragma unroll
  for (int bi = 0; bi < 16; bi++) {
    float v = best[bi];
    int idx = bi_[bi];
#pragma unroll
    for (int off = 8; off; off >>= 1) {
      float ov = __shfl_xor(v, off, 64);
      int oi = __shfl_xor(idx, off, 64);
      if (ov < v || (ov == v && oi < idx)) { v = ov; idx = oi; }
    }
    if (m16 == 0) {
      const int m = wm * 64 + (bi >> 2) * 16 + q4 * 4 + (bi & 3);
      mv[wn * 128 + m] = v;
      mi[wn * 128 + m] = idx;
    }
  }
  __syncthreads();
  // cross-wn merge (4 column partitions per row), tie -> smaller index
  if (t < 128) {
    float v = mv[t];
    int idx = mi[t];
#pragma unroll
    for (int p = 1; p < 4; p++) {
      float ov = mv[p * 128 + t];
      int oi = mi[p * 128 + t];
      if (ov < v || (ov == v && oi < idx)) { v = ov; idx = oi; }
    }
    ynew_out[row0 + t] = (float)idx;
  }

  // block 0: reduce the 4096 loss partials (prep is stream-ordered first)
  if (blockIdx.x == 0) {
    float s = 0.f;
#pragma unroll
    for (int j = 0; j < 8; j++) s += partial[t + 512 * j];
#pragma unroll
    for (int off = 32; off; off >>= 1) s += __shfl_down(s, off, 64);
    if (l == 0) ls[w] = s;
    __syncthreads();
    if (t == 0) {
      float tot = 0.f;
#pragma unroll
      for (int i = 0; i < 8; i++) tot += ls[i];
      loss_out[0] = tot;
    }
  }
}

__global__ __launch_bounds__(256) void loss_final(const float* __restrict__ partial,
                                                  float* __restrict__ out) {
  float s = 0.f;
#pragma unroll
  for (int j = 0; j < 64; j++) s += partial[threadIdx.x + 256 * j];
#pragma unroll
  for (int off = 32; off; off >>= 1) s += __shfl_down(s, off, 64);
  __shared__ float ps[4];
  if ((threadIdx.x & 63) == 0) ps[threadIdx.x >> 6] = s;
  __syncthreads();
  if (threadIdx.x == 0) out[0] = ps[0] + ps[1] + ps[2] + ps[3];
}

// ================= FALLBACK PATH (unchanged, used only if ws too small) =================

#define SLOT(row, oct) (16 * (oct) + (((row) & 15) ^ (((oct) & 2) << 1)))

__device__ __forceinline__ void split_pack(const float4& a, const float4& b,
                                           uint4& hi, uint4& lo) {
  float f[8] = {a.x, a.y, a.z, a.w, b.x, b.y, b.z, b.w};
  uint hw[4], lw[4];
#pragma unroll
  for (int i = 0; i < 4; i++) {
    uint e0 = __float_as_uint(f[2 * i]), e1 = __float_as_uint(f[2 * i + 1]);
    hw[i] = (e0 >> 16) | (e1 & 0xffff0000u);
    float l0 = f[2 * i]     - __uint_as_float(e0 & 0xffff0000u);
    float l1 = f[2 * i + 1] - __uint_as_float(e1 & 0xffff0000u);
    lw[i] = (__float_as_uint(l0) >> 16) | (__float_as_uint(l1) & 0xffff0000u);
  }
  hi = make_uint4(hw[0], hw[1], hw[2], hw[3]);
  lo = make_uint4(lw[0], lw[1], lw[2], lw[3]);
}

__global__ __launch_bounds__(256) void c2_kernel(const float* __restrict__ centers,
                                                 float* __restrict__ c2) {
  int wave = (blockIdx.x * 256 + threadIdx.x) >> 6;
  int lane = threadIdx.x & 63;
  const float4* c4 = (const float4*)(centers + (size_t)wave * DD);
  float s = 0.f;
#pragma unroll
  for (int j = 0; j < 2; j++) {
    float4 v = c4[lane + 64 * j];
    s += v.x * v.x + v.y * v.y + v.z * v.z + v.w * v.w;
  }
#pragma unroll
  for (int off = 32; off; off >>= 1) s += __shfl_down(s, off, 64);
  if (lane == 0) c2[wave] = s;
}

__global__ __launch_bounds__(256, 2) void argmin_fb(
    const float* __restrict__ x, const float* __restrict__ centers,
    const float* __restrict__ c2, float* __restrict__ ynew_out) {
  __shared__ uint4 Ah[512], Al[512], Bh[512], Bl[512];
  const int t = threadIdx.x;
  const int w = t >> 6, l = t & 63;
  const int wm = w >> 1, wn = w & 1;
  const size_t row0 = (size_t)blockIdx.x * 128;
  const int srow = t >> 1, h = t & 1;
  const int mt = srow >> 4;
  const int so0 = mt * 64 + SLOT(srow, 2 * h);
  const int so1 = mt * 64 + SLOT(srow, 2 * h + 1);
  const int rs = SLOT(l & 15, l >> 4);
  const float* xp = x + (row0 + srow) * DD + h * 16;
  float best[16];
  int bidx[16];
#pragma unroll
  for (int i = 0; i < 16; i++) { best[i] = 3.4e38f; bidx[i] = 0; }
  for (int n0 = 0; n0 < KC; n0 += 128) {
    const float* bp = centers + (size_t)(n0 + srow) * DD + h * 16;
    f32x4 acc[4][4];
#pragma unroll
    for (int i = 0; i < 4; i++)
#pragma unroll
      for (int j = 0; j < 4; j++) acc[i][j] = (f32x4){0.f, 0.f, 0.f, 0.f};
    float4 ra[4], rb[4];
#pragma unroll
    for (int q = 0; q < 4; q++) {
      ra[q] = *(const float4*)(xp + q * 4);
      rb[q] = *(const float4*)(bp + q * 4);
    }
    for (int ks = 0; ks < 16; ks++) {
      uint4 ah0, al0, ah1, al1, bh0, bl0, bh1, bl1;
      split_pack(ra[0], ra[1], ah0, al0);
      split_pack(ra[2], ra[3], ah1, al1);
      split_pack(rb[0], rb[1], bh0, bl0);
      split_pack(rb[2], rb[3], bh1, bl1);
      __syncthreads();
      Ah[so0] = ah0; Al[so0] = al0;
      Ah[so1] = ah1; Al[so1] = al1;
      Bh[so0] = bh0; Bl[so0] = bl0;
      Bh[so1] = bh1; Bl[so1] = bl1;
      __syncthreads();
      if (ks < 15) {
#pragma unroll
        for (int q = 0; q < 4; q++) {
          ra[q] = *(const float4*)(xp + (ks + 1) * 32 + q * 4);
          rb[q] = *(const float4*)(bp + (ks + 1) * 32 + q * 4);
        }
      }
      bf16x8 afh[4], afl[4], bfh[4], bfl[4];
#pragma unroll
      for (int i = 0; i < 4; i++) {
        afh[i] = *(const bf16x8*)&Ah[(wm * 4 + i) * 64 + rs];
        afl[i] = *(const bf16x8*)&Al[(wm * 4 + i) * 64 + rs];
        bfh[i] = *(const bf16x8*)&Bh[(wn * 4 + i) * 64 + rs];
        bfl[i] = *(const bf16x8*)&Bl[(wn * 4 + i) * 64 + rs];
      }
#pragma unroll
      for (int i = 0; i < 4; i++)
#pragma unroll
        for (int j = 0; j < 4; j++) {
          acc[i][j] = __builtin_amdgcn_mfma_f32_16x16x32_bf16(afh[i], bfh[j], acc[i][j], 0, 0, 0);
          acc[i][j] = __builtin_amdgcn_mfma_f32_16x16x32_bf16(afl[i], bfh[j], acc[i][j], 0, 0, 0);
          acc[i][j] = __builtin_amdgcn_mfma_f32_16x16x32_bf16(afh[i], bfl[j], acc[i][j], 0, 0, 0);
        }
    }
#pragma unroll
    for (int j = 0; j < 4; j++) {
      int n = n0 + wn * 64 + j * 16 + (l & 15);
      float cc = c2[n];
#pragma unroll
      for (int i = 0; i < 4; i++)
#pragma unroll
        for (int r = 0; r < 4; r++) {
          float v = fmaf(-2.f, acc[i][j][r], cc);
          int bi = i * 4 + r;
          if (v < best[bi]) { best[bi] = v; bidx[bi] = n; }
        }
    }
  }
#pragma unroll
  for (int bi = 0; bi < 16; bi++) {
    float v = best[bi];
    int idx = bidx[bi];
#pragma unroll
    for (int off = 8; off; off >>= 1) {
      float ov = __shfl_xor(v, off, 64);
      int oi = __shfl_xor(idx, off, 64);
      if (ov < v || (ov == v && oi < idx)) { v = ov; idx = oi; }
    }
    if ((l & 15) == 0) {
      int m = wm * 64 + (bi >> 2) * 16 + (l >> 4) * 4 + (bi & 3);
      ynew_out[row0 + m] = (float)idx;
    }
  }
}

__global__ __launch_bounds__(256) void loss_partial_fb(
    const float* __restrict__ x, const int* __restrict__ y,
    const float* __restrict__ centers, float* __restrict__ partial) {
  const int w = threadIdx.x >> 6, l = threadIdx.x & 63;
  const int row = blockIdx.x * 4 + w;
  const float4* x4 = (const float4*)(x + (size_t)row * DD);
  const float4* c4 = (const float4*)(centers + (size_t)y[row] * DD);
  float s = 0.f;
#pragma unroll
  for (int j = 0; j < 2; j++) {
    float4 xv = x4[2 * l + j], cv = c4[2 * l + j];
    float dx = xv.x - cv.x, dy = xv.y - cv.y, dz = xv.z - cv.z, dw = xv.w - cv.w;
    s += dx * dx + dy * dy + dz * dz + dw * dw;
  }
#pragma unroll
  for (int off = 32; off; off >>= 1) s += __shfl_down(s, off, 64);
  __shared__ float ps[4];
  if (l == 0) ps[w] = s;
  __syncthreads();
  if (threadIdx.x == 0) partial[blockIdx.x] = ps[0] + ps[1] + ps[2] + ps[3];
}

// ================= launcher =================

extern "C" void kernel_launch(void* const* d_in, const int* in_sizes, int n_in,
                              void* d_out, int out_size, void* d_ws, size_t ws_size,
                              hipStream_t stream) {
  const float* x       = (const float*)d_in[0];
  const int*   y       = (const int*)d_in[1];
  const float* centers = (const float*)d_in[2];
  float* out = (float*)d_out;  // out[0] = loss, out[1..] = ynew as float

  const size_t xb_bytes = (size_t)NPTS * DD * 2;  // 64 MB
  const size_t cb_bytes = (size_t)KC * DD * 2;    // 1 MB
  const size_t need = xb_bytes + cb_bytes + (KC + NPTS / 4) * sizeof(float);

  if (ws_size >= need) {
    uint4* xb      = (uint4*)d_ws;
    uint4* cbT     = (uint4*)((char*)d_ws + xb_bytes);
    float* c2      = (float*)((char*)d_ws + xb_bytes + cb_bytes);
    float* partial = c2 + KC;        // 4096 floats used (16384 reserved)
    prep_kernel<<<4096 + 256, 256, 0, stream>>>(x, y, centers, xb, cbT, c2, partial);
    gemm_argmin<<<NPTS / 128, 512, 0, stream>>>(xb, cbT, c2, partial, out, out + 1);
  } else {
    float* c2      = (float*)d_ws;
    float* partial = c2 + KC;
    c2_kernel<<<KC / 4, 256, 0, stream>>>(centers, c2);
    argmin_fb<<<NPTS / 128, 256, 0, stream>>>(x, centers, c2, out + 1);
    loss_partial_fb<<<NPTS / 4, 256, 0, stream>>>(x, y, centers, partial);
    loss_final<<<1, 256, 0, stream>>>(partial, out);
  }
}

// Round 7
// 274.336 us; speedup vs baseline: 1.0802x; 1.0802x over previous
//
#include <hip/hip_runtime.h>

#define NPTS 65536
#define KC   1024
#define DD   512

using bf16x8 = __attribute__((ext_vector_type(8))) __bf16;
using f32x4  = __attribute__((ext_vector_type(4))) float;

// ---- async global->LDS, 16B per lane. LDS dest = wave-uniform base + lane*16.
__device__ __forceinline__ void gld_lds16(const void* g, void* lds_base) {
  __builtin_amdgcn_global_load_lds(
      (const __attribute__((address_space(1))) unsigned int*)(uintptr_t)g,
      (__attribute__((address_space(3))) unsigned int*)(unsigned int)(uintptr_t)lds_base,
      16, 0, 0);
}

// pack float4 -> 4 bf16 (truncation)
__device__ __forceinline__ uint2 pack4(const float4& v) {
  uint2 r;
  r.x = (__float_as_uint(v.x) >> 16) | (__float_as_uint(v.y) & 0xffff0000u);
  r.y = (__float_as_uint(v.z) >> 16) | (__float_as_uint(v.w) & 0xffff0000u);
  return r;
}

// ================= FAST PATH =================

// merged prep (R4 structure): blocks [0,4096) = x section, 4 rows/wave;
// blocks [4096,4352) = centers section -> K-major cbT [kt][col][chunk]
// (16B chunk l of row c at uint4 index (l>>2)*4096 + c*4 + (l&3)) so gemm's
// direct-from-L2 B loads are coalesced 1KB wave reads.
// R2 LESSON: no single-address atomics.
__global__ __launch_bounds__(256) void prep_kernel(
    const float* __restrict__ x, const int* __restrict__ y,
    const float* __restrict__ centers, uint4* __restrict__ xb,
    uint4* __restrict__ cbT, float* __restrict__ c2,
    float* __restrict__ partial) {
  const int w = threadIdx.x >> 6, l = threadIdx.x & 63;
  if (blockIdx.x >= 4096) {   // centers section
    const int row = (blockIdx.x - 4096) * 4 + w;
    const float4* cf4 = (const float4*)centers;
    float4 a = cf4[row * 128 + 2 * l];
    float4 b = cf4[row * 128 + 2 * l + 1];
    uint2 pa = pack4(a), pb = pack4(b);
    cbT[(l >> 2) * 4096 + row * 4 + (l & 3)] = make_uint4(pa.x, pa.y, pb.x, pb.y);
    float s = a.x * a.x + a.y * a.y + a.z * a.z + a.w * a.w +
              b.x * b.x + b.y * b.y + b.z * b.z + b.w * b.w;
#pragma unroll
    for (int off = 32; off; off >>= 1) s += __shfl_down(s, off, 64);
    if (l == 0) c2[row] = s;
    return;
  }
  const int rbase = blockIdx.x * 16 + w * 4;
  const float4* xr = (const float4*)(x + (size_t)rbase * DD);
  float4 a[4], b[4];
#pragma unroll
  for (int r = 0; r < 4; r++) {
    a[r] = xr[r * 128 + 2 * l];
    b[r] = xr[r * 128 + 2 * l + 1];
  }
  int yr[4];
#pragma unroll
  for (int r = 0; r < 4; r++) yr[r] = y[rbase + r];
  float4 ca[4], cb4[4];
#pragma unroll
  for (int r = 0; r < 4; r++) {
    const float4* cr = (const float4*)(centers + (size_t)yr[r] * DD);
    ca[r]  = cr[2 * l];
    cb4[r] = cr[2 * l + 1];
  }
#pragma unroll
  for (int r = 0; r < 4; r++) {
    uint2 pa = pack4(a[r]), pb = pack4(b[r]);
    xb[(size_t)(rbase + r) * 64 + l] = make_uint4(pa.x, pa.y, pb.x, pb.y);
  }
  float s = 0.f;
#pragma unroll
  for (int r = 0; r < 4; r++) {
    float d0 = a[r].x - ca[r].x, d1 = a[r].y - ca[r].y;
    float d2 = a[r].z - ca[r].z, d3 = a[r].w - ca[r].w;
    float d4 = b[r].x - cb4[r].x, d5 = b[r].y - cb4[r].y;
    float d6 = b[r].z - cb4[r].z, d7 = b[r].w - cb4[r].w;
    s += d0 * d0 + d1 * d1 + d2 * d2 + d3 * d3 +
         d4 * d4 + d5 * d5 + d6 * d6 + d7 * d7;
  }
#pragma unroll
  for (int off = 32; off; off >>= 1) s += __shfl_down(s, off, 64);
  __shared__ float ps[4];
  if (l == 0) ps[w] = s;
  __syncthreads();
  if (threadIdx.x == 0) partial[blockIdx.x] = ps[0] + ps[1] + ps[2] + ps[3];
}

// bf16 MFMA argmin — R7: pipe-balanced geometry.
//
// R6 lesson: B-from-L2 rate = 4070*WARPS_M/BM B/cyc/CU; R6's 64x64 waves hit
// 64 B/cyc = 39 TB/s > 34.5 L2 ceiling -> structurally stuck at 27%.
// R4/R5 lesson: both-operands-in-LDS = 1540 cyc/tile LDS vs 1242 MFMA ->
// LDS-pipe-limited at ~36% across 3 different schedules.
//
// R7 geometry satisfies both pipes:
//  - BM=128, BN=256 (4 passes), BK=32.  256 threads = 4 waves, wave tile
//    128x64 (WARPS_M=1 -> B-L2 = 4070/128 = 32 B/cyc = 20 TB/s OK).
//  - A via gld_lds 4-slot ring (32KB LDS + 4KB c2s) -> 2 blocks/CU:
//    DESYNCED blocks finally give cross-block MFMA/VMEM/LDS overlap.
//  - B straight from L2 (cbT layout) into ping-pong regs bA/bB (static
//    names, rule 20); lead = 1 tile (~1200cy) >> L2 latency; compiler
//    emits its own counted waits for them.
//  - LDS reads/tile/CU ~40KB = 768 cyc < MFMA 1242 cyc.
//  - argmin state: 32 rows/lane -> INDEX PACKED into low 10 mantissa bits
//    of distance (stomp <=0.25, << bf16 GEMM noise; fminf = min+tiebreak).
// Ring: stage A(t+3) in tile t -> slot (t-1)&3 (read done, barrier passed).
// Boundary: vmcnt(8) = B(t+1) 4 + A(t+2) 2 + A(t+3) 2 in flight; force
// A(t+1).  Tail: 6 @ t=61, 4 @ t=62.  No setprio (m190).
// Regs: acc 128 AGPR + ~100 VGPR <= 256 @ (256,2).  Spill tripwire: WRITE.
__global__ __launch_bounds__(256, 2) void gemm_argmin(
    const uint4* __restrict__ xb, const uint4* __restrict__ cbT,
    const float* __restrict__ c2, const float* __restrict__ partial,
    float* __restrict__ loss_out, float* __restrict__ ynew_out) {
  __shared__ uint4 As[2048];   // 4 ring slots x (128 rows x 4 chunks)
  __shared__ float c2s[KC];
  __shared__ float ls[4];

  const int t = threadIdx.x;
  const int w = t >> 6, l = t & 63;      // w == wn: column quadrant
  const int q4 = l >> 4, m16 = l & 15;
  const int row0 = blockIdx.x * 128;

#pragma unroll
  for (int i = 0; i < 4; i++) c2s[t + 256 * i] = c2[t + 256 * i];

  // A staging: wave w stages rows [32w,32w+32) in two 16-row gld_lds calls;
  // source chunk pre-swizzled by the involution (rule 21), LDS dest linear.
  const int srow = l >> 2;
  const int schk = (l & 3) ^ ((l >> 3) & 3);
  const uint4* aBlo = xb + ((size_t)(row0 + w * 32 + srow) * 64 + schk);
  const uint4* aBhi = aBlo + 16 * 64;
  // fragment-read chunk: same XOR
  const int xs = q4 ^ ((m16 >> 1) & 3);
  // B lane offset within a (kt, pass) 1KB panel slice
  const int bl0 = w * 256 + m16 * 4 + q4;

  // prologue: stage A tiles 0..2 (slots 0..2), load B(0)
#pragma unroll
  for (int p = 0; p < 3; p++) {
    gld_lds16(aBlo + p * 4, &As[p * 512 + w * 128]);
    gld_lds16(aBhi + p * 4, &As[p * 512 + w * 128 + 64]);
  }
  bf16x8 bA[4], bB[4];
#pragma unroll
  for (int j = 0; j < 4; j++)
    bA[j] = *(const bf16x8*)(cbT + bl0 + j * 64);

  f32x4 acc[8][4];
#pragma unroll
  for (int i = 0; i < 8; i++)
#pragma unroll
    for (int j = 0; j < 4; j++) acc[i][j] = (f32x4){0.f, 0.f, 0.f, 0.f};

  float best[32];
#pragma unroll
  for (int i = 0; i < 32; i++) best[i] = 3.4e38f;

  // issued: A0(2) A1(2) A2(2) B0(4) = 10; force A0 -> allow 8
  asm volatile("s_waitcnt vmcnt(8)" ::: "memory");
  __builtin_amdgcn_s_barrier();

#define FOLD(P)                                                             \
  {                                                                         \
    _Pragma("unroll")                                                       \
    for (int j = 0; j < 4; j++) {                                           \
      const int n = (P) * 256 + w * 64 + j * 16 + m16;                      \
      const float cc = c2s[n];                                              \
      _Pragma("unroll")                                                     \
      for (int i = 0; i < 8; i++)                                           \
        _Pragma("unroll")                                                   \
        for (int r = 0; r < 4; r++) {                                       \
          float v = fmaf(-2.f, acc[i][j][r], cc);                           \
          uint pk = (__float_as_uint(v) & 0xFFFFFC00u) | (uint)n;           \
          const int bx = i * 4 + r;                                         \
          best[bx] = fminf(best[bx], __uint_as_float(pk));                  \
          acc[i][j][r] = 0.f;                                               \
        }                                                                   \
    }                                                                       \
  }

#define TILE(T, BC, BN)                                                     \
  {                                                                         \
    const int bse = ((T) & 3) * 512;                                        \
    if ((T) < 63) {  /* B(t+1) -> BN (compiler-counted loads) */            \
      const int tn = (T) + 1;                                               \
      const uint4* bp = cbT + (tn & 15) * 4096 + (tn >> 4) * 1024;          \
      _Pragma("unroll")                                                     \
      for (int j = 0; j < 4; j++)                                           \
        BN[j] = *(const bf16x8*)(bp + bl0 + j * 64);                        \
    }                                                                       \
    if ((T) <= 60) { /* stage A(t+3) -> slot (t-1)&3 */                     \
      const int s2 = (((T) + 3) & 3) * 512;                                 \
      const int oa = (((T) + 3) & 15) * 4;                                  \
      gld_lds16(aBlo + oa, &As[s2 + w * 128]);                              \
      gld_lds16(aBhi + oa, &As[s2 + w * 128 + 64]);                         \
    }                                                                       \
    _Pragma("unroll")                                                       \
    for (int i = 0; i < 8; i++) {                                           \
      bf16x8 af = *(const bf16x8*)&As[bse + (i * 16 + m16) * 4 + xs];       \
      _Pragma("unroll")                                                     \
      for (int j = 0; j < 4; j++)                                           \
        acc[i][j] = __builtin_amdgcn_mfma_f32_16x16x32_bf16(af, BC[j], acc[i][j], 0, 0, 0); \
    }                                                                       \
    if (((T) & 15) == 15) FOLD((T) >> 4);                                   \
    if ((T) <= 60)      asm volatile("s_waitcnt vmcnt(8)" ::: "memory");    \
    else if ((T) == 61) asm volatile("s_waitcnt vmcnt(6)" ::: "memory");    \
    else if ((T) == 62) asm volatile("s_waitcnt vmcnt(4)" ::: "memory");    \
    if ((T) < 63) __builtin_amdgcn_s_barrier();                             \
  }

#pragma unroll 1
  for (int s = 0; s < 32; ++s) {
    const int te = 2 * s;
    TILE(te, bA, bB);
    TILE(te + 1, bB, bA);
  }
#undef TILE
#undef FOLD

  __syncthreads();   // drain everything; As reused for the merge

  // min-reduce across the 16 m16-lanes (index rides in the low bits)
  float* mv = (float*)As;                 // [4 wn][128 rows]
#pragma unroll
  for (int bi = 0; bi < 32; bi++) {
    float v = best[bi];
#pragma unroll
    for (int off = 8; off; off >>= 1) v = fminf(v, __shfl_xor(v, off, 64));
    if (m16 == 0) {
      const int row = (bi >> 2) * 16 + q4 * 4 + (bi & 3);
      mv[w * 128 + row] = v;
    }
  }
  __syncthreads();
  // cross-quadrant merge + decode
  if (t < 128) {
    float v = fminf(fminf(mv[t], mv[128 + t]), fminf(mv[256 + t], mv[384 + t]));
    ynew_out[row0 + t] = (float)(__float_as_uint(v) & 1023u);
  }

  // block 0: reduce the 4096 loss partials (prep is stream-ordered first)
  if (blockIdx.x == 0) {
    float s = 0.f;
#pragma unroll
    for (int j = 0; j < 16; j++) s += partial[t + 256 * j];
#pragma unroll
    for (int off = 32; off; off >>= 1) s += __shfl_down(s, off, 64);
    if (l == 0) ls[w] = s;
    __syncthreads();
    if (t == 0) ls[0] = ls[0] + ls[1] + ls[2] + ls[3];
    __syncthreads();
    if (t == 0) loss_out[0] = ls[0];
  }
}

__global__ __launch_bounds__(256) void loss_final(const float* __restrict__ partial,
                                                  float* __restrict__ out) {
  float s = 0.f;
#pragma unroll
  for (int j = 0; j < 64; j++) s += partial[threadIdx.x + 256 * j];
#pragma unroll
  for (int off = 32; off; off >>= 1) s += __shfl_down(s, off, 64);
  __shared__ float ps[4];
  if ((threadIdx.x & 63) == 0) ps[threadIdx.x >> 6] = s;
  __syncthreads();
  if (threadIdx.x == 0) out[0] = ps[0] + ps[1] + ps[2] + ps[3];
}

// ================= FALLBACK PATH (unchanged, used only if ws too small) =================

#define SLOT(row, oct) (16 * (oct) + (((row) & 15) ^ (((oct) & 2) << 1)))

__device__ __forceinline__ void split_pack(const float4& a, const float4& b,
                                           uint4& hi, uint4& lo) {
  float f[8] = {a.x, a.y, a.z, a.w, b.x, b.y, b.z, b.w};
  uint hw[4], lw[4];
#pragma unroll
  for (int i = 0; i < 4; i++) {
    uint e0 = __float_as_uint(f[2 * i]), e1 = __float_as_uint(f[2 * i + 1]);
    hw[i] = (e0 >> 16) | (e1 & 0xffff0000u);
    float l0 = f[2 * i]     - __uint_as_float(e0 & 0xffff0000u);
    float l1 = f[2 * i + 1] - __uint_as_float(e1 & 0xffff0000u);
    lw[i] = (__float_as_uint(l0) >> 16) | (__float_as_uint(l1) & 0xffff0000u);
  }
  hi = make_uint4(hw[0], hw[1], hw[2], hw[3]);
  lo = make_uint4(lw[0], lw[1], lw[2], lw[3]);
}

__global__ __launch_bounds__(256) void c2_kernel(const float* __restrict__ centers,
                                                 float* __restrict__ c2) {
  int wave = (blockIdx.x * 256 + threadIdx.x) >> 6;
  int lane = threadIdx.x & 63;
  const float4* c4 = (const float4*)(centers + (size_t)wave * DD);
  float s = 0.f;
#pragma unroll
  for (int j = 0; j < 2; j++) {
    float4 v = c4[lane + 64 * j];
    s += v.x * v.x + v.y * v.y + v.z * v.z + v.w * v.w;
  }
#pragma unroll
  for (int off = 32; off; off >>= 1) s += __shfl_down(s, off, 64);
  if (lane == 0) c2[wave] = s;
}

__global__ __launch_bounds__(256, 2) void argmin_fb(
    const float* __restrict__ x, const float* __restrict__ centers,
    const float* __restrict__ c2, float* __restrict__ ynew_out) {
  __shared__ uint4 Ah[512], Al[512], Bh[512], Bl[512];
  const int t = threadIdx.x;
  const int w = t >> 6, l = t & 63;
  const int wm = w >> 1, wn = w & 1;
  const size_t row0 = (size_t)blockIdx.x * 128;
  const int srow = t >> 1, h = t & 1;
  const int mt = srow >> 4;
  const int so0 = mt * 64 + SLOT(srow, 2 * h);
  const int so1 = mt * 64 + SLOT(srow, 2 * h + 1);
  const int rs = SLOT(l & 15, l >> 4);
  const float* xp = x + (row0 + srow) * DD + h * 16;
  float best[16];
  int bidx[16];
#pragma unroll
  for (int i = 0; i < 16; i++) { best[i] = 3.4e38f; bidx[i] = 0; }
  for (int n0 = 0; n0 < KC; n0 += 128) {
    const float* bp = centers + (size_t)(n0 + srow) * DD + h * 16;
    f32x4 acc[4][4];
#pragma unroll
    for (int i = 0; i < 4; i++)
#pragma unroll
      for (int j = 0; j < 4; j++) acc[i][j] = (f32x4){0.f, 0.f, 0.f, 0.f};
    float4 ra[4], rb[4];
#pragma unroll
    for (int q = 0; q < 4; q++) {
      ra[q] = *(const float4*)(xp + q * 4);
      rb[q] = *(const float4*)(bp + q * 4);
    }
    for (int ks = 0; ks < 16; ks++) {
      uint4 ah0, al0, ah1, al1, bh0, bl0, bh1, bl1;
      split_pack(ra[0], ra[1], ah0, al0);
      split_pack(ra[2], ra[3], ah1, al1);
      split_pack(rb[0], rb[1], bh0, bl0);
      split_pack(rb[2], rb[3], bh1, bl1);
      __syncthreads();
      Ah[so0] = ah0; Al[so0] = al0;
      Ah[so1] = ah1; Al[so1] = al1;
      Bh[so0] = bh0; Bl[so0] = bl0;
      Bh[so1] = bh1; Bl[so1] = bl1;
      __syncthreads();
      if (ks < 15) {
#pragma unroll
        for (int q = 0; q < 4; q++) {
          ra[q] = *(const float4*)(xp + (ks + 1) * 32 + q * 4);
          rb[q] = *(const float4*)(bp + (ks + 1) * 32 + q * 4);
        }
      }
      bf16x8 afh[4], afl[4], bfh[4], bfl[4];
#pragma unroll
      for (int i = 0; i < 4; i++) {
        afh[i] = *(const bf16x8*)&Ah[(wm * 4 + i) * 64 + rs];
        afl[i] = *(const bf16x8*)&Al[(wm * 4 + i) * 64 + rs];
        bfh[i] = *(const bf16x8*)&Bh[(wn * 4 + i) * 64 + rs];
        bfl[i] = *(const bf16x8*)&Bl[(wn * 4 + i) * 64 + rs];
      }
#pragma unroll
      for (int i = 0; i < 4; i++)
#pragma unroll
        for (int j = 0; j < 4; j++) {
          acc[i][j] = __builtin_amdgcn_mfma_f32_16x16x32_bf16(afh[i], bfh[j], acc[i][j], 0, 0, 0);
          acc[i][j] = __builtin_amdgcn_mfma_f32_16x16x32_bf16(afl[i], bfh[j], acc[i][j], 0, 0, 0);
          acc[i][j] = __builtin_amdgcn_mfma_f32_16x16x32_bf16(afh[i], bfl[j], acc[i][j], 0, 0, 0);
        }
    }
#pragma unroll
    for (int j = 0; j < 4; j++) {
      int n = n0 + wn * 64 + j * 16 + (l & 15);
      float cc = c2[n];
#pragma unroll
      for (int i = 0; i < 4; i++)
#pragma unroll
        for (int r = 0; r < 4; r++) {
          float v = fmaf(-2.f, acc[i][j][r], cc);
          int bi = i * 4 + r;
          if (v < best[bi]) { best[bi] = v; bidx[bi] = n; }
        }
    }
  }
#pragma unroll
  for (int bi = 0; bi < 16; bi++) {
    float v = best[bi];
    int idx = bidx[bi];
#pragma unroll
    for (int off = 8; off; off >>= 1) {
      float ov = __shfl_xor(v, off, 64);
      int oi = __shfl_xor(idx, off, 64);
      if (ov < v || (ov == v && oi < idx)) { v = ov; idx = oi; }
    }
    if ((l & 15) == 0) {
      int m = wm * 64 + (bi >> 2) * 16 + (l >> 4) * 4 + (bi & 3);
      ynew_out[row0 + m] = (float)idx;
    }
  }
}

__global__ __launch_bounds__(256) void loss_partial_fb(
    const float* __restrict__ x, const int* __restrict__ y,
    const float* __restrict__ centers, float* __restrict__ partial) {
  const int w = threadIdx.x >> 6, l = threadIdx.x & 63;
  const int row = blockIdx.x * 4 + w;
  const float4* x4 = (const float4*)(x + (size_t)row * DD);
  const float4* c4 = (const float4*)(centers + (size_t)y[row] * DD);
  float s = 0.f;
#pragma unroll
  for (int j = 0; j < 2; j++) {
    float4 xv = x4[2 * l + j], cv = c4[2 * l + j];
    float dx = xv.x - cv.x, dy = xv.y - cv.y, dz = xv.z - cv.z, dw = xv.w - cv.w;
    s += dx * dx + dy * dy + dz * dz + dw * dw;
  }
#pragma unroll
  for (int off = 32; off; off >>= 1) s += __shfl_down(s, off, 64);
  __shared__ float ps[4];
  if (l == 0) ps[w] = s;
  __syncthreads();
  if (threadIdx.x == 0) partial[blockIdx.x] = ps[0] + ps[1] + ps[2] + ps[3];
}

// ================= launcher =================

extern "C" void kernel_launch(void* const* d_in, const int* in_sizes, int n_in,
                              void* d_out, int out_size, void* d_ws, size_t ws_size,
                              hipStream_t stream) {
  const float* x       = (const float*)d_in[0];
  const int*   y       = (const int*)d_in[1];
  const float* centers = (const float*)d_in[2];
  float* out = (float*)d_out;  // out[0] = loss, out[1..] = ynew as float

  const size_t xb_bytes = (size_t)NPTS * DD * 2;  // 64 MB
  const size_t cb_bytes = (size_t)KC * DD * 2;    // 1 MB
  const size_t need = xb_bytes + cb_bytes + (KC + NPTS / 4) * sizeof(float);

  if (ws_size >= need) {
    uint4* xb      = (uint4*)d_ws;
    uint4* cbT     = (uint4*)((char*)d_ws + xb_bytes);
    float* c2      = (float*)((char*)d_ws + xb_bytes + cb_bytes);
    float* partial = c2 + KC;        // 4096 floats used (16384 reserved)
    prep_kernel<<<4096 + 256, 256, 0, stream>>>(x, y, centers, xb, cbT, c2, partial);
    gemm_argmin<<<NPTS / 128, 256, 0, stream>>>(xb, cbT, c2, partial, out, out + 1);
  } else {
    float* c2      = (float*)d_ws;
    float* partial = c2 + KC;
    c2_kernel<<<KC / 4, 256, 0, stream>>>(centers, c2);
    argmin_fb<<<NPTS / 128, 256, 0, stream>>>(x, centers, c2, out + 1);
    loss_partial_fb<<<NPTS / 4, 256, 0, stream>>>(x, y, centers, partial);
    loss_final<<<1, 256, 0, stream>>>(partial, out);
  }
}